// Round 16
// baseline (78.018 us; speedup 1.0000x reference)
//
#include <hip/hip_runtime.h>
#include <math.h>

namespace {

constexpr int   MTOT = 4096;
constexpr float H    = 0.1f;

// W_FACTORS = sqrt((0.5^2 + sigma^2)/2), sigma in {0.4, 0.8, 1.2, 1.6}
constexpr float W0 = 0.45276925690687087f;
constexpr float W1 = 0.66708320320631664f;
constexpr float W2 = 0.91923881554251174f;
constexpr float W3 = 1.18532695911296985f;

constexpr float KCOUL   = 14.399645478425669f;
constexpr float HALF_L1 = 2.8867513459481287f;  // 0.5*sqrt(3)/0.3
constexpr float SQRTPI  = 1.7724538509055159f;
constexpr float TWOSQPI = 1.1283791670955126f;  // 2/sqrt(pi)

// k_r = 0.5/W_r
constexpr float K0 = 1.1043153f, K1 = 0.74953184f, K2 = 0.54392830f, K3 = 0.42182454f;

// A&S 7.1.25 (|err|<=2.5e-5): pk=0.47047*k, c2=-k^2*log2e
constexpr float PK0 = 0.5195472f, PK1 = 0.3526314f, PK2 = 0.2559019f, PK3 = 0.1984558f;
constexpr float C20 = -1.7593842f, C21 = -0.8105028f, C22 = -0.4268329f, C23 = -0.2567073f;
constexpr float EA1 = 0.3480242f, EA2 = -0.0958798f, EA3 = 0.7478556f;
constexpr float RCP_H = 9.9999000f, RCP_HS2 = 7.0710178f, RCP_2H = 4.9999750f;

// g/Gt tables: 256 entries, h = 0.03, d in [0, 7.68)
constexpr int   TGN   = 256;
constexpr float TG_H  = 0.03f;
constexpr float INV_G = 33.333332f;

// near tier: exact 7-site path when any lane center-distance < 2
constexpr float NEAR2 = 4.0f;

// ws layout (float4 units): [0,256) gV | [256,512) gD | [512,768) tV | [768,1024) tD
// [1024 + g*256 + i) pos4 sorted | +128 chg4 sorted. orig: int[] after 9216 float4.
constexpr int WS_GRAPH_BASE = 1024;
constexpr int WS_ORIG_F4    = 9216;   // byte offset = 9216*16

__device__ __forceinline__ float fast_rcp(float x)  { return __builtin_amdgcn_rcpf(x); }
__device__ __forceinline__ float fast_rsq(float x)  { return __builtin_amdgcn_rsqf(x); }
__device__ __forceinline__ float fast_exp2(float x) { return __builtin_amdgcn_exp2f(x); }

// q = erfc-part of A&S 7.1.25; erf = 1 - q
__device__ __forceinline__ float erf_q(float d, float d2, float pk, float c2) {
  float t = fast_rcp(__builtin_fmaf(d, pk, 1.0f));
  float poly = t * __builtin_fmaf(t, __builtin_fmaf(t, EA3, EA2), EA1);
  return poly * fast_exp2(d2 * c2);
}

// g(d)=erf(kd)/d ; Gt(d)=0.2*(erf/d^3 - (2k/sqrt(pi))e^{-k^2d^2}/d^2); series small-d
__device__ __forceinline__ float g_of(float k, float d) {
  const float k2d2 = k * k * d * d;
  if (d < 0.5f)
    return TWOSQPI * k * (1.0f - k2d2 * (1.0f / 3.0f) + k2d2 * k2d2 * 0.1f);
  return erff(k * d) / d;
}
__device__ __forceinline__ float gt_of(float k, float d) {
  const float k2d2 = k * k * d * d;
  if (d < 0.5f)
    return 0.2f * TWOSQPI * k * k * k *
           (2.0f / 3.0f - 0.4f * k2d2 + k2d2 * k2d2 * (1.0f / 7.0f));
  const float e = erff(k * d), x = expf(-k2d2);
  return 0.2f * e / (d * d * d) - 0.2f * TWOSQPI * k * x / (d * d);
}

__device__ __forceinline__ float project_one(const float* S, int k) {
  if (k < 4) return S[k];
  int q = k - 4;
  int r = q / 3;
  int comp = q - 3 * r;
  int j1, j2;
  if (comp == 0)      { j1 = 2; j2 = 5; }
  else if (comp == 1) { j1 = 3; j2 = 6; }
  else                { j1 = 1; j2 = 4; }
  return HALF_L1 * (S[j1 * 4 + r] - S[j2 * 4 + r]);
}

__device__ __forceinline__ unsigned spread3(int v) {
  return (unsigned)((v & 1) | ((v & 2) << 2) | ((v & 4) << 4));
}

// ---------------- prep: block 0 builds g/Gt tables; blocks 1..32 sort graphs ----
__global__ __launch_bounds__(256) void es_prep(
    const float* __restrict__ sf, const float* __restrict__ pos,
    float4* __restrict__ ws4, int* __restrict__ wsOrig)
{
  const int b   = blockIdx.x;
  const int tid = threadIdx.x;

  if (b == 0) {
    // g/Gt tables, 256 entries
    const float d0 = tid * TG_H;
    const float d1 = (tid + 1) * TG_H;
    const float ks[4] = {K0, K1, K2, K3};
    float gv[4], gd[4], tv[4], td[4];
#pragma unroll
    for (int r = 0; r < 4; ++r) {
      const float k  = ks[r];
      const float g0 = g_of(k, d0),  g1 = g_of(k, d1);
      const float t0 = gt_of(k, d0), t1 = gt_of(k, d1);
      gv[r] = g0; gd[r] = g1 - g0; tv[r] = t0; td[r] = t1 - t0;
    }
    ws4[tid]       = make_float4(gv[0], gv[1], gv[2], gv[3]);
    ws4[256 + tid] = make_float4(gd[0], gd[1], gd[2], gd[3]);
    ws4[512 + tid] = make_float4(tv[0], tv[1], tv[2], tv[3]);
    ws4[768 + tid] = make_float4(td[0], td[1], td[2], td[3]);
    return;
  }

  // sort one graph
  __shared__ unsigned s_key[128];
  const int g = b - 1;
  float px = 0.f, py = 0.f, pz = 0.f;
  float4 myc = make_float4(0.f, 0.f, 0.f, 0.f);
  if (tid < 128) {
    const float* p = pos + (size_t)(g * 128 + tid) * 3;
    px = p[0]; py = p[1]; pz = p[2];
    const float4 s = ((const float4*)sf)[g * 128 + tid];
    myc = make_float4(s.x, 5.0f * s.w, 5.0f * s.y, 5.0f * s.z);  // {s0,5s3,5s1,5s2}
    int cx = (int)((px + 16.0f) * 0.25f); cx = (cx < 0) ? 0 : (cx > 7 ? 7 : cx);
    int cy = (int)((py + 16.0f) * 0.25f); cy = (cy < 0) ? 0 : (cy > 7 ? 7 : cy);
    int cz = (int)((pz + 16.0f) * 0.25f); cz = (cz < 0) ? 0 : (cz > 7 ? 7 : cz);
    unsigned mort = spread3(cx) | (spread3(cy) << 1) | (spread3(cz) << 2);
    s_key[tid] = (mort << 7) | (unsigned)tid;
  }
  __syncthreads();
  if (tid < 128) {
    const unsigned mykey = s_key[tid];
    int rank = 0;
    for (int t = 0; t < 128; ++t) rank += (s_key[t] < mykey) ? 1 : 0;
    ws4[WS_GRAPH_BASE + g * 256 + rank]       = make_float4(px, py, pz, 0.0f);
    ws4[WS_GRAPH_BASE + g * 256 + 128 + rank] = myc;
    wsOrig[g * 128 + rank] = tid;
  }
}

// ---------------- main: 1024 blocks = 32 graphs x 32 site-blocks (28 sites) ----
// block: 448 thr = 28 sites x 16 chunks of 8 source nodes. 4 blocks/CU, 28 waves/CU.
__global__ __launch_bounds__(448, 7) void es_main(
    const float4* __restrict__ ws4, const int* __restrict__ wsOrig,
    float* __restrict__ out)
{
  __shared__ float4 s_tabs[1024];   // gV | gD | tV | tD (256 each)
  __shared__ float4 s_pos4[128];
  __shared__ float4 s_chg4[128];
  __shared__ int    s_orig[128];
  __shared__ float4 s_part[448];    // 16 chunks x 28 sites
  __shared__ float  s_feat[112];
  __shared__ float  s_self[112];

  const int b   = blockIdx.x;
  const int g   = b >> 5;    // graph
  const int sb  = b & 31;    // site-block: sites [sb*28, sb*28+28) = nodes [sb*4, sb*4+4)
  const int tid = threadIdx.x;

  // ---- prologue: coalesced L2->LDS copy ----
  for (int i = tid; i < 1024; i += 448) s_tabs[i] = ws4[i];
  if (tid < 128) {
    s_pos4[tid] = ws4[WS_GRAPH_BASE + g * 256 + tid];
    s_chg4[tid] = ws4[WS_GRAPH_BASE + g * 256 + 128 + tid];
    s_orig[tid] = wsOrig[g * 128 + tid];
  }
  __syncthreads();

  // ---- per-thread target site ----
  const int site_local = tid % 28;
  const int chunk      = tid / 28;         // 0..15, 8 source nodes each
  const int sl   = sb * 28 + site_local;   // target site in graph [0,896), sorted
  const int jown = (sl * 9363) >> 16;      // own node slot
  const int aoff = sl - jown * 7;

  const float4 cp = s_pos4[jown];
  const float tx = cp.x + ((aoff == 1) ? H : (aoff == 4) ? -H : 0.0f);
  const float ty = cp.y + ((aoff == 2) ? H : (aoff == 5) ? -H : 0.0f);
  const float tz = cp.z + ((aoff == 3) ? H : (aoff == 6) ? -H : 0.0f);

  float a0 = 0.f, a1 = 0.f, a2 = 0.f, a3 = 0.f, Ssat = 0.f;

  // exact site-pair accumulate via analytic 7.1.25 (matches epilogue exactly)
  auto acc_full = [&](float d2raw, float c) {
    float d2 = fmaxf(d2raw, 1e-12f);
    float rd = fast_rsq(d2);
    float d  = d2 * rd;
    float cv = c * rd;
    a0 = __builtin_fmaf(cv, 1.0f - erf_q(d, d2, PK0, C20), a0);
    a1 = __builtin_fmaf(cv, 1.0f - erf_q(d, d2, PK1, C21), a1);
    a2 = __builtin_fmaf(cv, 1.0f - erf_q(d, d2, PK2, C22), a2);
    a3 = __builtin_fmaf(cv, 1.0f - erf_q(d, d2, PK3, C23), a3);
  };

  const int j0 = chunk * 8;
#pragma unroll
  for (int jj = 0; jj < 8; ++jj) {
    const int j = j0 + jj;
    const float4 p4 = s_pos4[j];
    const float4 c4 = s_chg4[j];
    const float vx = tx - p4.x;
    const float vy = ty - p4.y;
    const float vz = tz - p4.z;
    const float v2 = __builtin_fmaf(vx, vx, __builtin_fmaf(vy, vy, vz * vz));
    if (__any(v2 < NEAR2)) {
      // NEAR: exact 7-site analytic path; mask the singular own-site pair
      const float w2 = v2 + 0.01f;
      const bool own = (j == jown);
      acc_full(v2,                            (own & (aoff == 0)) ? 0.0f :  c4.x);
      acc_full(__builtin_fmaf(vx, -0.2f, w2), (own & (aoff == 1)) ? 0.0f :  c4.y);
      acc_full(__builtin_fmaf(vy, -0.2f, w2), (own & (aoff == 2)) ? 0.0f :  c4.z);
      acc_full(__builtin_fmaf(vz, -0.2f, w2), (own & (aoff == 3)) ? 0.0f :  c4.w);
      acc_full(__builtin_fmaf(vx,  0.2f, w2), (own & (aoff == 4)) ? 0.0f : -c4.y);
      acc_full(__builtin_fmaf(vy,  0.2f, w2), (own & (aoff == 5)) ? 0.0f : -c4.z);
      acc_full(__builtin_fmaf(vz,  0.2f, w2), (own & (aoff == 6)) ? 0.0f : -c4.w);
    } else {
      const float rd  = fast_rsq(v2);
      const float dot = __builtin_fmaf(c4.y, vx, __builtin_fmaf(c4.z, vy, c4.w * vz));
      const float d   = v2 * rd;
      if (d * INV_G < (float)(TGN - 1) ? __any(d * INV_G < (float)(TGN - 1)) : false) {
        // (kept wave-uniform below)
      }
      if (__any(v2 < 58.9f)) {   // any lane possibly inside table range (7.68^2)
        // MID: monopole + dipole via tables, per-lane analytic fallback
        const float t   = d * INV_G;
        const int   idx = (int)t;
        const bool  in  = (idx < TGN - 1);
        const int   ic  = in ? idx : (TGN - 2);
        const float f   = fminf(t - (float)idx, 1.0f);
        const float4 Gv = s_tabs[ic];
        const float4 Gd = s_tabs[256 + ic];
        const float4 Tv = s_tabs[512 + ic];
        const float4 Td = s_tabs[768 + ic];
        const float gs  = rd;
        const float ts  = 0.2f * rd * rd * rd;
        const float g0v = in ? __builtin_fmaf(Gd.x, f, Gv.x) : gs;
        const float g1v = in ? __builtin_fmaf(Gd.y, f, Gv.y) : gs;
        const float g2v = in ? __builtin_fmaf(Gd.z, f, Gv.z) : gs;
        const float g3v = in ? __builtin_fmaf(Gd.w, f, Gv.w) : gs;
        const float t0v = in ? __builtin_fmaf(Td.x, f, Tv.x) : ts;
        const float t1v = in ? __builtin_fmaf(Td.y, f, Tv.y) : ts;
        const float t2v = in ? __builtin_fmaf(Td.z, f, Tv.z) : ts;
        const float t3v = in ? __builtin_fmaf(Td.w, f, Tv.w) : ts;
        a0 = __builtin_fmaf(c4.x, g0v, __builtin_fmaf(dot, t0v, a0));
        a1 = __builtin_fmaf(c4.x, g1v, __builtin_fmaf(dot, t1v, a1));
        a2 = __builtin_fmaf(c4.x, g2v, __builtin_fmaf(dot, t2v, a2));
        a3 = __builtin_fmaf(c4.x, g3v, __builtin_fmaf(dot, t3v, a3));
      } else {
        // SAT: analytic monopole + dipole
        Ssat = __builtin_fmaf(c4.x, rd, Ssat);
        Ssat = __builtin_fmaf(0.2f * dot, rd * rd * rd, Ssat);
      }
    }
  }
  a0 += Ssat; a1 += Ssat; a2 += Ssat; a3 += Ssat;

  s_part[chunk * 28 + site_local] = make_float4(a0, a1, a2, a3);
  __syncthreads();

  // ---- reduce chunks + self term + own-node correction (cancels to +c_a*diag) ----
  if (tid < 112) {
    const int site = tid >> 2;   // 0..27
    const int r    = tid & 3;
    const float* pf = (const float*)s_part;
    float tot = 0.f;
#pragma unroll
    for (int c = 0; c < 16; ++c) tot += pf[c * 112 + tid];

    const float w  = (r == 0) ? W0  : (r == 1) ? W1  : (r == 2) ? W2  : W3;
    const float pk = (r == 0) ? PK0 : (r == 1) ? PK1 : (r == 2) ? PK2 : PK3;
    const float c2 = (r == 0) ? C20 : (r == 1) ? C21 : (r == 2) ? C22 : C23;
    const float diag = fast_rcp(w * SQRTPI);
    const float ph1 = (1.f - erf_q(0.1f,        0.01f, pk, c2)) * RCP_H;
    const float ph2 = (1.f - erf_q(0.14142136f, 0.02f, pk, c2)) * RCP_HS2;
    const float ph3 = (1.f - erf_q(0.2f,        0.04f, pk, c2)) * RCP_2H;

    const int jn = (site * 9363) >> 16;  // node within block's 4 nodes
    const int ba = site - jn * 7;
    const float4 c4 = s_chg4[sb * 4 + jn];
    float selfSum = 0.f, ca = 0.f;
#pragma unroll
    for (int i = 0; i < 7; ++i) {
      const float ci = (i == 0) ?  c4.x : (i == 1) ?  c4.y : (i == 2) ?  c4.z :
                       (i == 3) ?  c4.w : (i == 4) ? -c4.y : (i == 5) ? -c4.z : -c4.w;
      float ph;
      if (i == ba)                             ph = diag;
      else if (i == 0 || ba == 0)              ph = ph1;
      else if ((i - ba == 3) || (ba - i == 3)) ph = ph3;
      else                                     ph = ph2;
      selfSum = __builtin_fmaf(ci, ph, selfSum);
      if (i == ba) ca = ci;
    }
    s_self[tid] = KCOUL * selfSum;
    s_feat[tid] = KCOUL * __builtin_fmaf(ca, diag, tot);
  }
  __syncthreads();

  // ---- projection + write (map sorted node -> original id) ----
  if (tid < 64) {
    const int nl = tid >> 4;   // 0..3
    const int k  = tid & 15;
    const int m  = g * 128 + s_orig[sb * 4 + nl];
    float vf = project_one(&s_feat[nl * 28], k);
    float vs = project_one(&s_self[nl * 28], k);
    out[m * 16 + k]             = vf;
    out[MTOT * 16 + m * 16 + k] = vs;
  }
}

} // namespace

extern "C" void kernel_launch(void* const* d_in, const int* in_sizes, int n_in,
                              void* d_out, int out_size, void* d_ws, size_t ws_size,
                              hipStream_t stream) {
  const float* sf  = (const float*)d_in[0];   // source_feats (4096,1,4)
  const float* pos = (const float*)d_in[1];   // node_positions (4096,3)
  float*  out    = (float*)d_out;
  float4* ws4    = (float4*)d_ws;
  int*    wsOrig = (int*)((char*)d_ws + (size_t)WS_ORIG_F4 * 16);
  es_prep<<<33, 256, 0, stream>>>(sf, pos, ws4, wsOrig);
  es_main<<<1024, 448, 0, stream>>>(ws4, wsOrig, out);
}